// Round 11
// baseline (343.473 us; speedup 1.0000x reference)
//
#include <hip/hip_runtime.h>
#include <math.h>

#define BB 4
#define SS 2048
#define DD 1024
#define MM (BB*SS)                   // 8192
#define SD ((size_t)SS*DD)
#define MD ((size_t)MM*DD)           // 8,388,608
#define PPB ((size_t)2162688)        // packed P elems per batch

// ws (bf16 elems): Q@0 | K@MD | VT@2MD | P@3MD (4*PPB) | WT (6*DD*DD) | zpad(16) | L (8192 f32)
#define WT_OFF (3*MD + 4*PPB)
#define ZP_OFF (WT_OFF + 6*(size_t)DD*DD)
#define LF_OFF (ZP_OFF + 16)
#define REQ_WS ((LF_OFF + 16384) * 2)

constexpr float LN_EPS = 1e-6f;

typedef __attribute__((ext_vector_type(8))) __bf16 bf16x8;
typedef __attribute__((ext_vector_type(4))) float f32x4;

__device__ __forceinline__ unsigned short f2bfbits(float f){
    unsigned u = __float_as_uint(f);
    u += 0x7FFFu + ((u >> 16) & 1u);   // RNE
    return (unsigned short)(u >> 16);
}
__device__ __forceinline__ int rowWidth(int s){ return ((s >> 6) + 1) << 6; }
__device__ __forceinline__ size_t rowOff(int s){
    int g = s >> 6;
    return (size_t)4096 * (size_t)((g * (g + 1)) >> 1) + (size_t)(s & 63) * (size_t)((g + 1) << 6);
}
// async global->LDS, 16B per lane; LDS dest = wave-uniform base + lane*16
__device__ __forceinline__ void gl_lds(const unsigned short* g, unsigned short* l){
    __builtin_amdgcn_global_load_lds(
        (const __attribute__((address_space(1))) unsigned int*)g,
        (__attribute__((address_space(3))) unsigned int*)l, 16, 0, 0);
}

__global__ __launch_bounds__(256)
void sentinel_kernel(float* __restrict__ out, const float val){
    out[(size_t)blockIdx.x * 256 + threadIdx.x] = val;
}

// ---------- prep: fused {weight transpose + zpad/L zero} and {LayerNorm1} ----------
struct WPack { const float* w[6]; unsigned short* o[6]; unsigned short* zp; float* lf; };
struct PrepArgs { WPack wp; const float* x; const float* g1; const float* be1;
                  unsigned short* ln; };
__global__ __launch_bounds__(256)
void prep(PrepArgs pa)
{
    const int id = blockIdx.x;
    const int tid = threadIdx.x;
    if (id < 1536){
        __shared__ float Ts[64][65];
        const int z = id >> 8, rem = id & 255;
        const int yy = rem >> 4, xx = rem & 15;
        const float* W = pa.wp.w[z];
        unsigned short* WT = pa.wp.o[z];
        const int r0 = yy*64, c0 = xx*64;
        if (id == 0 && tid < 16) pa.wp.zp[tid] = 0;
        if (id < 16){                       // zero L[8192] f32
            float2 z2 = {0.f, 0.f};
            ((float2*)pa.wp.lf)[id*256 + tid] = z2;
        }
        #pragma unroll
        for (int i = 0; i < 16; ++i){
            int lin = tid + i*256;
            int r = lin >> 6, c = lin & 63;
            Ts[r][c] = W[(size_t)(r0+r)*DD + c0+c];
        }
        __syncthreads();
        #pragma unroll
        for (int i = 0; i < 16; ++i){
            int lin = tid + i*256;
            int r = lin >> 6, c = lin & 63;
            WT[(size_t)(c0+r)*DD + r0+c] = f2bfbits(Ts[c][r]);
        }
    } else {
        __shared__ float red[4];
        const int row = id - 1536;
        float4 xv = ((const float4*)(pa.x + (size_t)row*DD))[tid];
        float v[4] = {xv.x, xv.y, xv.z, xv.w};
        float s = v[0]+v[1]+v[2]+v[3];
        #pragma unroll
        for (int off = 32; off > 0; off >>= 1) s += __shfl_down(s, off, 64);
        if ((tid & 63) == 0) red[tid >> 6] = s;
        __syncthreads();
        const float mean = (red[0]+red[1]+red[2]+red[3]) * (1.0f/DD);
        __syncthreads();
        float q = 0.f;
        #pragma unroll
        for (int i = 0; i < 4; ++i){ float d = v[i]-mean; q += d*d; }
        #pragma unroll
        for (int off = 32; off > 0; off >>= 1) q += __shfl_down(q, off, 64);
        if ((tid & 63) == 0) red[tid >> 6] = q;
        __syncthreads();
        const float var = (red[0]+red[1]+red[2]+red[3]) * (1.0f/(DD-1));
        const float inv = 1.0f/(sqrtf(var) + LN_EPS);
        float4 g4 = ((const float4*)pa.g1)[tid];
        float4 b4 = ((const float4*)pa.be1)[tid];
        ushort4 o;
        o.x = f2bfbits(g4.x*(v[0]-mean)*inv + b4.x);
        o.y = f2bfbits(g4.y*(v[1]-mean)*inv + b4.y);
        o.z = f2bfbits(g4.z*(v[2]-mean)*inv + b4.z);
        o.w = f2bfbits(g4.w*(v[3]-mean)*inv + b4.w);
        ((ushort4*)(pa.ln + (size_t)row*DD))[tid] = o;
    }
}

// ---------- LayerNorm: fp32 in -> bf16 out (standalone, for LN2) ----------
__global__ __launch_bounds__(256)
void ln_f32(const float* __restrict__ x, const float* __restrict__ gamma,
            const float* __restrict__ beta, unsigned short* __restrict__ out)
{
    __shared__ float red[4];
    const int row = blockIdx.x;
    const int tid = threadIdx.x;
    float4 xv = ((const float4*)(x + (size_t)row*DD))[tid];
    float v[4] = {xv.x, xv.y, xv.z, xv.w};
    float s = v[0]+v[1]+v[2]+v[3];
    #pragma unroll
    for (int off = 32; off > 0; off >>= 1) s += __shfl_down(s, off, 64);
    if ((tid & 63) == 0) red[tid >> 6] = s;
    __syncthreads();
    const float mean = (red[0]+red[1]+red[2]+red[3]) * (1.0f/DD);
    __syncthreads();
    float q = 0.f;
    #pragma unroll
    for (int i = 0; i < 4; ++i){ float d = v[i]-mean; q += d*d; }
    #pragma unroll
    for (int off = 32; off > 0; off >>= 1) q += __shfl_down(q, off, 64);
    if ((tid & 63) == 0) red[tid >> 6] = q;
    __syncthreads();
    const float var = (red[0]+red[1]+red[2]+red[3]) * (1.0f/(DD-1));
    const float inv = 1.0f/(sqrtf(var) + LN_EPS);
    float4 g4 = ((const float4*)gamma)[tid];
    float4 b4 = ((const float4*)beta)[tid];
    ushort4 o;
    o.x = f2bfbits(g4.x*(v[0]-mean)*inv + b4.x);
    o.y = f2bfbits(g4.y*(v[1]-mean)*inv + b4.y);
    o.z = f2bfbits(g4.z*(v[2]-mean)*inv + b4.z);
    o.w = f2bfbits(g4.w*(v[3]-mean)*inv + b4.w);
    ((ushort4*)(out + (size_t)row*DD))[tid] = o;
}

// ============================================================================
// 8-phase-style 256x128 GEMM core (K=1024 fixed, 16 K-tiles fully unrolled).
// 8 waves (4M x 2N, per-wave 64x64 out, acc 4x4 f32x4). Triple-buffered LDS
// (144 KB, R3-proven static size), granule-rotated rows (conflict-free).
// Per phase (2 per K-tile): 8x ds_read_b128 -> issue 3 gl_lds (tile t+2)
// -> raw barrier -> lgkmcnt(0)+sched_barrier -> setprio{16 MFMA} ->
// [tile end: counted vmcnt(6), depth-2 prefetch, never 0 mid-loop] -> barrier.
// ============================================================================
__device__ __forceinline__ void mk8a(const unsigned short* base, size_t ld, int r0,
                                     int wave, int lane, const unsigned short* g[4]){
    #pragma unroll
    for (int c = 0; c < 4; ++c){
        const int mr = (c*8 + wave)*8 + (lane >> 3);      // 0..255
        const int gk = ((lane & 7) - mr) & 7;
        g[c] = base + (size_t)(r0 + mr)*ld + gk*8;
    }
}
__device__ __forceinline__ void mk8b(const unsigned short* base, size_t ld, int r0,
                                     int wave, int lane, const unsigned short* g[2]){
    #pragma unroll
    for (int c = 0; c < 2; ++c){
        const int mr = (c*8 + wave)*8 + (lane >> 3);      // 0..127
        const int gk = ((lane & 7) - mr) & 7;
        g[c] = base + (size_t)(r0 + mr)*ld + gk*8;
    }
}

template<bool STAGE, bool WAIT0>
__device__ __forceinline__ void t_step(
    const unsigned short* const ga[4], const unsigned short* const gb[2], const int kS,
    f32x4 (&acc)[4][4], const int wave, const int lane,
    unsigned short (&RA)[16384], unsigned short (&RB)[8192],
    unsigned short (&SA)[16384], unsigned short (&SB)[8192])
{
    const int quad = lane >> 4, l15 = lane & 15;
    const int wm = (wave >> 1) * 64;       // 0,64,128,192
    const int wn = (wave & 1) * 64;        // 0,64
    #pragma unroll
    for (int kk = 0; kk < 2; ++kk){
        bf16x8 af[4], bf[4];
        #pragma unroll
        for (int f = 0; f < 4; ++f){
            const int ra = wm + f*16 + l15, rb = wn + f*16 + l15, gi = kk*4 + quad;
            af[f] = *(const bf16x8*)&RA[ra*64 + (((gi + ra) & 7) << 3)];
            bf[f] = *(const bf16x8*)&RB[rb*64 + (((gi + rb) & 7) << 3)];
        }
        if constexpr (STAGE){
            if (kk == 0){
                gl_lds(ga[0] + kS, &SA[(0*8 + wave)*512]);
                gl_lds(ga[1] + kS, &SA[(1*8 + wave)*512]);
                gl_lds(ga[2] + kS, &SA[(2*8 + wave)*512]);
            } else {
                gl_lds(ga[3] + kS, &SA[(3*8 + wave)*512]);
                gl_lds(gb[0] + kS, &SB[(0*8 + wave)*512]);
                gl_lds(gb[1] + kS, &SB[(1*8 + wave)*512]);
            }
        }
        __builtin_amdgcn_s_barrier();
        asm volatile("s_waitcnt lgkmcnt(0)" ::: "memory");
        __builtin_amdgcn_sched_barrier(0);
        __builtin_amdgcn_s_setprio(1);
        #pragma unroll
        for (int i = 0; i < 4; ++i)
            #pragma unroll
            for (int j = 0; j < 4; ++j)
                acc[i][j] = __builtin_amdgcn_mfma_f32_16x16x32_bf16(af[i], bf[j], acc[i][j], 0, 0, 0);
        __builtin_amdgcn_s_setprio(0);
        if (kk == 1){
            if constexpr (WAIT0) asm volatile("s_waitcnt vmcnt(0)" ::: "memory");
            else                 asm volatile("s_waitcnt vmcnt(6)" ::: "memory");
        }
        __builtin_amdgcn_s_barrier();
    }
}

#define DECL_TRI \
    __shared__ unsigned short A0[16384]; __shared__ unsigned short B0[8192]; \
    __shared__ unsigned short A1[16384]; __shared__ unsigned short B1[8192]; \
    __shared__ unsigned short A2[16384]; __shared__ unsigned short B2[8192];

template<bool RELU, bool RES, bool OUTF, bool BIAS_M>
__device__ __forceinline__ void gemm8_core(
    const unsigned short* __restrict__ A, const unsigned short* __restrict__ B,
    const float* __restrict__ bias, const float* __restrict__ resF,
    unsigned short* __restrict__ outB, float* __restrict__ outF,
    const int N, const int lda, const int ldb, const int m0, const int n0,
    unsigned short (&A0)[16384], unsigned short (&B0)[8192],
    unsigned short (&A1)[16384], unsigned short (&B1)[8192],
    unsigned short (&A2)[16384], unsigned short (&B2)[8192])
{
    const int tid = threadIdx.x, lane = tid & 63, wave = tid >> 6;
    const unsigned short* ga[4]; const unsigned short* gb[2];
    mk8a(A, lda, m0, wave, lane, ga);
    mk8b(B, ldb, n0, wave, lane, gb);
    f32x4 acc[4][4] = {};

    // prologue: tile0 -> P0, tile1 -> P1; wait tile0 (tile1 stays in flight)
    #pragma unroll
    for (int c = 0; c < 4; ++c) gl_lds(ga[c],      &A0[(c*8 + wave)*512]);
    #pragma unroll
    for (int c = 0; c < 2; ++c) gl_lds(gb[c],      &B0[(c*8 + wave)*512]);
    #pragma unroll
    for (int c = 0; c < 4; ++c) gl_lds(ga[c] + 64, &A1[(c*8 + wave)*512]);
    #pragma unroll
    for (int c = 0; c < 2; ++c) gl_lds(gb[c] + 64, &B1[(c*8 + wave)*512]);
    asm volatile("s_waitcnt vmcnt(6)" ::: "memory");
    __builtin_amdgcn_s_barrier();

    // 16 K-tiles, read t%3, stage tile t+2 into buffer (t+2)%3
    t_step<true ,false>(ga, gb, 128, acc, wave, lane, A0,B0, A2,B2);  // t0
    t_step<true ,false>(ga, gb, 192, acc, wave, lane, A1,B1, A0,B0);  // t1
    t_step<true ,false>(ga, gb, 256, acc, wave, lane, A2,B2, A1,B1);  // t2
    t_step<true ,false>(ga, gb, 320, acc, wave, lane, A0,B0, A2,B2);  // t3
    t_step<true ,false>(ga, gb, 384, acc, wave, lane, A1,B1, A0,B0);  // t4
    t_step<true ,false>(ga, gb, 448, acc, wave, lane, A2,B2, A1,B1);  // t5
    t_step<true ,false>(ga, gb, 512, acc, wave, lane, A0,B0, A2,B2);  // t6
    t_step<true ,false>(ga, gb, 576, acc, wave, lane, A1,B1, A0,B0);  // t7
    t_step<true ,false>(ga, gb, 640, acc, wave, lane, A2,B2, A1,B1);  // t8
    t_step<true ,false>(ga, gb, 704, acc, wave, lane, A0,B0, A2,B2);  // t9
    t_step<true ,false>(ga, gb, 768, acc, wave, lane, A1,B1, A0,B0);  // t10
    t_step<true ,false>(ga, gb, 832, acc, wave, lane, A2,B2, A1,B1);  // t11
    t_step<true ,false>(ga, gb, 896, acc, wave, lane, A0,B0, A2,B2);  // t12
    t_step<true ,false>(ga, gb, 960, acc, wave, lane, A1,B1, A0,B0);  // t13
    t_step<false,true >(ga, gb, 0,   acc, wave, lane, A2,B2, A2,B2);  // t14 (drain)
    t_step<false,true >(ga, gb, 0,   acc, wave, lane, A0,B0, A0,B0);  // t15

    const int quad = lane >> 4, l15 = lane & 15;
    const int wm = (wave >> 1) * 64, wn = (wave & 1) * 64;
    #pragma unroll
    for (int i = 0; i < 4; ++i){
        #pragma unroll
        for (int r = 0; r < 4; ++r){
            const int m = m0 + wm + i*16 + quad*4 + r;
            const float bm = BIAS_M ? bias[m] : 0.f;
            #pragma unroll
            for (int j = 0; j < 4; ++j){
                const int n = n0 + wn + j*16 + l15;
                float v = acc[i][j][r] + (BIAS_M ? bm : bias[n]);
                if constexpr (RELU) v = fmaxf(v, 0.f);
                if constexpr (RES) v += resF[(size_t)m*N + n];
                if constexpr (OUTF) outF[(size_t)m*N + n] = v;
                else outB[(size_t)m*N + n] = f2bfbits(v);
            }
        }
    }
}

// dense GEMM on the 8-phase core: M=8192, N=1024, K=1024. 256 blocks = 1 GPU-wave.
template<bool RELU, bool RES, bool OUTF, bool BIAS_M>
__global__ __launch_bounds__(512)
void gemm8(const unsigned short* __restrict__ A, const unsigned short* __restrict__ B,
           const float* __restrict__ bias, const float* __restrict__ resF,
           unsigned short* __restrict__ outB, float* __restrict__ outF,
           const int N, const int lda, const int ldb)
{
    DECL_TRI
    const int lin = blockIdx.x;                  // 256
    const int id = (lin & 7) * 32 + (lin >> 3);  // chunked XCD swizzle
    const int m0 = (id >> 3) * 256, n0 = (id & 7) * 128;
    gemm8_core<RELU,RES,OUTF,BIAS_M>(A, B, bias, resF, outB, outF, N, lda, ldb,
                                     m0, n0, A0,B0,A1,B1,A2,B2);
}

// fused Q/K/VT projections on the 8-phase core: 768 blocks = 3 GPU-waves.
__global__ __launch_bounds__(512)
void proj8(const unsigned short* __restrict__ LN,
           const unsigned short* __restrict__ WqT, const unsigned short* __restrict__ WkT,
           const unsigned short* __restrict__ WvT,
           const float* __restrict__ bq, const float* __restrict__ bk,
           const float* __restrict__ bv,
           unsigned short* __restrict__ Qw, unsigned short* __restrict__ Kw,
           unsigned short* __restrict__ VTw)
{
    DECL_TRI
    const int lin = blockIdx.x;                  // 768
    const int id = (lin & 7) * 96 + (lin >> 3);  // chunked XCD swizzle
    if (id < 512){
        const bool isK = (id >= 256);
        const int q = id & 255;
        const int n0 = (q & 7) * 128, m0 = (q >> 3) * 256;   // n over DD, m over MM
        gemm8_core<false,false,false,false>(LN, isK ? WkT : WqT, isK ? bk : bq, nullptr,
                                            isK ? Kw : Qw, nullptr, DD, DD, DD,
                                            m0, n0, A0,B0,A1,B1,A2,B2);
    } else {
        const int v = id - 512;
        const int m0 = (v & 3) * 256, n0 = (v >> 2) * 128;   // m over DD, n over MM
        gemm8_core<false,false,false,true>(WvT, LN, bv, nullptr, VTw, nullptr,
                                           MM, DD, DD, m0, n0, A0,B0,A1,B1,A2,B2);
    }
}

// =========== 128^2 double-buffered core (kept for scores/pv, R8-proven) ===========
template<bool PACKED>
__device__ __forceinline__ void mfma_db(
    const unsigned short* const ga[4], const unsigned short* const gb[4],
    const int* pw, const unsigned short* zpad, const int NT,
    f32x4 acc[4][4], const int wave, const int lane,
    unsigned short (&As0)[8192], unsigned short (&Bs0)[8192],
    unsigned short (&As1)[8192], unsigned short (&Bs1)[8192])
{
    const int quad = lane >> 4, l15 = lane & 15;
    const int wm = ((wave >> 1) & 1) * 64, wn = (wave & 1) * 64;

    auto stage = [&](unsigned short (&Ab)[8192], unsigned short (&Bb)[8192], const int koff){
        #pragma unroll
        for (int c = 0; c < 4; ++c){
            const unsigned short* gp = ga[c] + koff;
            if constexpr (PACKED) { if (koff >= pw[c]) gp = zpad; }
            gl_lds(gp, &Ab[(wave*4+c)*512]);
            gl_lds(gb[c] + koff, &Bb[(wave*4+c)*512]);
        }
    };
    auto compute = [&](unsigned short (&Ab)[8192], unsigned short (&Bb)[8192]){
        #pragma unroll
        for (int kk = 0; kk < 2; ++kk){
            bf16x8 af[4], bfr[4];
            #pragma unroll
            for (int t = 0; t < 4; ++t){
                const int ra = wm + t*16 + l15, rb = wn + t*16 + l15, gi = kk*4 + quad;
                af[t]  = *(const bf16x8*)&Ab[ra*64 + (((gi + ra) & 7) << 3)];
                bfr[t] = *(const bf16x8*)&Bb[rb*64 + (((gi + rb) & 7) << 3)];
            }
            #pragma unroll
            for (int i = 0; i < 4; ++i)
                #pragma unroll
                for (int j = 0; j < 4; ++j)
                    acc[i][j] = __builtin_amdgcn_mfma_f32_16x16x32_bf16(af[i], bfr[j], acc[i][j], 0, 0, 0);
        }
    };

    stage(As0, Bs0, 0);
    const int half = NT >> 1;
    for (int i = 0; i < half; ++i){
        stage(As1, Bs1, (2*i + 1) << 6);
        asm volatile("s_waitcnt vmcnt(8)" ::: "memory");
        __builtin_amdgcn_s_barrier();
        __builtin_amdgcn_sched_barrier(0);
        compute(As0, Bs0);
        __builtin_amdgcn_s_barrier();
        if (i + 1 < half){
            stage(As0, Bs0, (2*i + 2) << 6);
            asm volatile("s_waitcnt vmcnt(8)" ::: "memory");
        } else {
            asm volatile("s_waitcnt vmcnt(0)" ::: "memory");
        }
        __builtin_amdgcn_s_barrier();
        __builtin_amdgcn_sched_barrier(0);
        compute(As1, Bs1);
        __builtin_amdgcn_s_barrier();
    }
}

__device__ __forceinline__ void mk_chunks(const unsigned short* base, size_t ld, int r0,
                                          int wave, int lane, const unsigned short* g[4]){
    #pragma unroll
    for (int c = 0; c < 4; ++c){
        const int mr = (wave*4 + c)*8 + (lane >> 3);
        const int gk = ((lane & 7) - mr) & 7;
        g[c] = base + (size_t)(r0 + mr)*ld + gk*8;
    }
}

#define DECL_DB \
    __shared__ unsigned short As0[8192]; \
    __shared__ unsigned short Bs0[8192]; \
    __shared__ unsigned short As1[8192]; \
    __shared__ unsigned short Bs1[8192];

// ---------- scores: packed P = exp(Q*K^T * scale), causal, UNNORMALIZED ----------
__global__ __launch_bounds__(256)
void scores_mfma(const unsigned short* __restrict__ Qb, const unsigned short* __restrict__ Kb,
                 unsigned short* __restrict__ Pb, float* __restrict__ Lf, const float scale)
{
    const int lin = blockIdx.x;                    // 544 = 4 * 136
    const int id = (lin & 7) * 68 + (lin >> 3);    // chunked XCD swizzle
    const int z = id / 136;
    const int idx = id - z * 136;
    int y = (int)((sqrtf(8.f * (float)idx + 1.f) - 1.f) * 0.5f);
    while ((y + 1) * (y + 2) / 2 <= idx) ++y;      // guard float error
    while (y * (y + 1) / 2 > idx) --y;
    const int x = idx - y * (y + 1) / 2;           // x <= y
    const int s0 = y * 128, t0 = x * 128;

    const unsigned short* Q  = Qb + (size_t)z*SD;
    const unsigned short* Km = Kb + (size_t)z*SD;
    unsigned short* P        = Pb + (size_t)z*PPB;
    float* L                 = Lf + (size_t)z*SS;
    DECL_DB
    const int tid = threadIdx.x, lane = tid & 63, wave = tid >> 6;
    const int wm = ((wave >> 1) & 1) * 64, wn = (wave & 1) * 64;
    const int quad = lane >> 4, l15 = lane & 15;
    const unsigned short* ga[4]; const unsigned short* gb[4];
    mk_chunks(Q,  DD, s0, wave, lane, ga);
    mk_chunks(Km, DD, t0, wave, lane, gb);
    f32x4 acc[4][4] = {};
    mfma_db<false>(ga, gb, nullptr, nullptr, DD >> 6, acc, wave, lane, As0, Bs0, As1, Bs1);

    #pragma unroll
    for (int i = 0; i < 4; ++i){
        #pragma unroll
        for (int r = 0; r < 4; ++r){
            const int s = s0 + wm + i*16 + quad*4 + r;
            const int width = rowWidth(s);
            unsigned short* pr = P + rowOff(s);
            float psum = 0.f;
            if (t0 + wn < width){                    // 64-chunk uniform in/out
                #pragma unroll
                for (int j = 0; j < 4; ++j){
                    const int t = t0 + wn + j*16 + l15;
                    const float e = (t <= s) ? __expf(acc[i][j][r] * scale) : 0.f;
                    pr[t] = f2bfbits(e);
                    psum += e;
                }
                #pragma unroll
                for (int off = 8; off > 0; off >>= 1) psum += __shfl_xor(psum, off, 64);
                if (l15 == 0) atomicAdd(&L[s], psum);
            }
        }
    }
}

// ---------- ctx = (P @ V) / l ; A=packed unnormalized P, B=VT[d][tok] ----------
__global__ __launch_bounds__(256)
void pv_mfma(const unsigned short* __restrict__ Pb, const unsigned short* __restrict__ VT,
             unsigned short* __restrict__ Cb, const unsigned short* __restrict__ zpad,
             const float* __restrict__ Lf)
{
    const int yr = blockIdx.y;
    const int y  = (blockIdx.z >= 2) ? (15 - yr) : yr;
    const int s0 = y*128, n0 = blockIdx.x*128;
    const unsigned short* P = Pb + (size_t)blockIdx.z*PPB;
    unsigned short* C       = Cb + (size_t)blockIdx.z*SD;
    const float* L          = Lf + (size_t)blockIdx.z*SS;
    const int bcol = blockIdx.z*SS;
    DECL_DB
    const int tid = threadIdx.x, lane = tid & 63, wave = tid >> 6;
    const int wm = ((wave >> 1) & 1) * 64, wn = (wave & 1) * 64;
    const int quad = lane >> 4, l15 = lane & 15;
    const unsigned short* ga[4]; const unsigned short* gb[4]; int pw[4];
    #pragma unroll
    for (int c = 0; c < 4; ++c){
        const int mr = (wave*4 + c)*8 + (lane >> 3);
        const int gk = ((lane & 7) - mr) & 7;
        const int s = s0 + mr;
        pw[c] = rowWidth(s) - gk*8;                 // chunk valid iff koff < pw
        ga[c] = P + rowOff(s) + gk*8;
    }
    mk_chunks(VT + bcol, MM, n0, wave, lane, gb);
    f32x4 acc[4][4] = {};
    const int NT = (s0 >> 6) + 2;                   // 2y+2, even
    mfma_db<true>(ga, gb, pw, zpad, NT, acc, wave, lane, As0, Bs0, As1, Bs1);

    #pragma unroll
    for (int i = 0; i < 4; ++i){
        #pragma unroll
        for (int r = 0; r < 4; ++r){
            const int s = s0 + wm + i*16 + quad*4 + r;
            const float linv = 1.0f / L[s];
            #pragma unroll
            for (int j = 0; j < 4; ++j){
                const int n = n0 + wn + j*16 + l15;
                C[(size_t)s*DD + n] = f2bfbits(acc[i][j][r] * linv);
            }
        }
    }
}

extern "C" void kernel_launch(void* const* d_in, const int* in_sizes, int n_in,
                              void* d_out, int out_size, void* d_ws, size_t ws_size,
                              hipStream_t stream)
{
    (void)in_sizes; (void)n_in; (void)out_size;
    const float* x   = (const float*)d_in[0];
    const float* bq  = (const float*)d_in[2];
    const float* bk  = (const float*)d_in[4];
    const float* bv  = (const float*)d_in[6];
    const float* bo  = (const float*)d_in[8];
    const float* b1  = (const float*)d_in[10];
    const float* b2  = (const float*)d_in[12];
    const float* g1  = (const float*)d_in[13];
    const float* be1 = (const float*)d_in[14];
    const float* g2  = (const float*)d_in[15];
    const float* be2 = (const float*)d_in[16];
    float* outf = (float*)d_out;

    if (ws_size < (size_t)REQ_WS){
        sentinel_kernel<<<dim3((unsigned)(MD/256)), dim3(256), 0, stream>>>(outf, 1.0e9f);
        return;
    }

    unsigned short* wsb = (unsigned short*)d_ws;
    unsigned short* Qw  = wsb;                 // -> ctx
    unsigned short* Kw  = wsb + MD;            // \ -> Hf (fp32 spans K+VT)
    unsigned short* VTw = wsb + 2*MD;          // /
    unsigned short* Pw  = wsb + 3*MD;          // packed P -> mid
    unsigned short* WT  = wsb + WT_OFF;
    unsigned short* ZP  = wsb + ZP_OFF;
    float*          Lf  = (float*)(wsb + LF_OFF);
    float*          Hf  = (float*)Kw;
    unsigned short* CTX = Qw;
    unsigned short* MIDw= Pw;
    unsigned short* LN  = (unsigned short*)d_out;   // LN1/LN2 scratch in d_out

    PrepArgs pa;
    static const int widx[6] = {1,3,5,7,9,11};
    for (int i = 0; i < 6; ++i){
        pa.wp.w[i] = (const float*)d_in[widx[i]];
        pa.wp.o[i] = WT + (size_t)i*DD*DD;
    }
    pa.wp.zp = ZP;
    pa.wp.lf = Lf;
    pa.x = x; pa.g1 = g1; pa.be1 = be1; pa.ln = LN;
    unsigned short* WqT = pa.wp.o[0]; unsigned short* WkT = pa.wp.o[1];
    unsigned short* WvT = pa.wp.o[2]; unsigned short* WoT = pa.wp.o[3];
    unsigned short* W1T = pa.wp.o[4]; unsigned short* W2T = pa.wp.o[5];

    const dim3 blk(256);
    const dim3 blk8(512);
    const float scale = 1.0f / sqrtf((float)SS);

    // fused wtrans + LN1 (independent streams, one launch)
    prep<<<dim3(1536 + MM), blk, 0, stream>>>(pa);
    // fused Q + K + VT projections (768 blocks of 512 thr, 8-phase core)
    proj8<<<dim3(768), blk8, 0, stream>>>(LN, WqT, WkT, WvT, bq, bk, bv, Qw, Kw, VTw);
    // attention: fused exp-scores (+row sums, triangular-packed) then PV (/rowsum)
    scores_mfma<<<dim3(544), blk, 0, stream>>>(Qw, Kw, Pw, Lf, scale);
    pv_mfma<<<dim3(DD/128, SS/128, BB), blk, 0, stream>>>(Pw, VTw, CTX, ZP, Lf);
    // h = ctx*WoT^T + bo + x (fp32)
    gemm8<false,true,true,false><<<dim3(256), blk8, 0, stream>>>(CTX, WoT, bo, x, nullptr, Hf, DD, DD, DD);
    ln_f32<<<dim3(MM), blk, 0, stream>>>(Hf, g2, be2, LN);
    // mid = relu(LN*W1T^T + b1)
    gemm8<true,false,false,false><<<dim3(256), blk8, 0, stream>>>(LN, W1T, b1, nullptr, MIDw, nullptr, DD, DD, DD);
    // out = mid*W2T^T + b2 + h
    gemm8<false,true,true,false><<<dim3(256), blk8, 0, stream>>>(MIDw, W2T, b2, Hf, nullptr, outf, DD, DD, DD);
}

// Round 12
// 342.358 us; speedup vs baseline: 1.0033x; 1.0033x over previous
//
#include <hip/hip_runtime.h>
#include <math.h>

#define BB 4
#define SS 2048
#define DD 1024
#define MM (BB*SS)                   // 8192
#define SD ((size_t)SS*DD)
#define MD ((size_t)MM*DD)           // 8,388,608
#define PPB ((size_t)2162688)        // packed P elems per batch

// ws (bf16 elems): Q@0 | K@MD | VT@2MD | P@3MD (4*PPB) | WT (6*DD*DD) | zpad(16) | L (8192 f32)
#define WT_OFF (3*MD + 4*PPB)
#define ZP_OFF (WT_OFF + 6*(size_t)DD*DD)
#define LF_OFF (ZP_OFF + 16)
#define REQ_WS ((LF_OFF + 16384) * 2)

constexpr float LN_EPS = 1e-6f;

typedef __attribute__((ext_vector_type(8))) __bf16 bf16x8;
typedef __attribute__((ext_vector_type(4))) float f32x4;

__device__ __forceinline__ unsigned short f2bfbits(float f){
    unsigned u = __float_as_uint(f);
    u += 0x7FFFu + ((u >> 16) & 1u);   // RNE
    return (unsigned short)(u >> 16);
}
__device__ __forceinline__ int rowWidth(int s){ return ((s >> 6) + 1) << 6; }
__device__ __forceinline__ size_t rowOff(int s){
    int g = s >> 6;
    return (size_t)4096 * (size_t)((g * (g + 1)) >> 1) + (size_t)(s & 63) * (size_t)((g + 1) << 6);
}
// async global->LDS, 16B per lane; LDS dest = wave-uniform base + lane*16
__device__ __forceinline__ void gl_lds(const unsigned short* g, unsigned short* l){
    __builtin_amdgcn_global_load_lds(
        (const __attribute__((address_space(1))) unsigned int*)g,
        (__attribute__((address_space(3))) unsigned int*)l, 16, 0, 0);
}

// XCD-aware bijective block swizzle (T1) — uniform-work launches only.
__device__ __forceinline__ int3 xcd_swz(){
    const int gx = gridDim.x, gy = gridDim.y, gz = gridDim.z;
    const int n = gx * gy * gz;
    int lin = blockIdx.x + gx * (blockIdx.y + gy * blockIdx.z);
    const int cpx = n >> 3;                 // n % 8 == 0 for all swizzled launches
    lin = (lin & 7) * cpx + (lin >> 3);     // bijection: XCD (lin&7) owns chunk
    int3 r;
    r.x = lin % gx; lin /= gx;
    r.y = lin % gy;
    r.z = lin / gy;
    return r;
}

__global__ __launch_bounds__(256)
void sentinel_kernel(float* __restrict__ out, const float val){
    out[(size_t)blockIdx.x * 256 + threadIdx.x] = val;
}

// ---------- prep: fused {weight transpose + zpad/L zero} and {LayerNorm1} ----------
// wtrans path vectorized (G13): float4 loads (16B/lane), ushort4 stores (8B/lane).
struct WPack { const float* w[6]; unsigned short* o[6]; unsigned short* zp; float* lf; };
struct PrepArgs { WPack wp; const float* x; const float* g1; const float* be1;
                  unsigned short* ln; };
__global__ __launch_bounds__(256)
void prep(PrepArgs pa)
{
    const int id = blockIdx.x;
    const int tid = threadIdx.x;
    if (id < 1536){
        __shared__ float Ts[64][65];
        const int z = id >> 8, rem = id & 255;
        const int yy = rem >> 4, xx = rem & 15;
        const float* W = pa.wp.w[z];
        unsigned short* WT = pa.wp.o[z];
        const int r0 = yy*64, c0 = xx*64;
        if (id == 0 && tid < 16) pa.wp.zp[tid] = 0;
        if (id < 16){                       // zero L[8192] f32
            float2 z2 = {0.f, 0.f};
            ((float2*)pa.wp.lf)[id*256 + tid] = z2;
        }
        // load 64x64 f32 tile as float4 (4 iters x 256 thr x 16B)
        #pragma unroll
        for (int i = 0; i < 4; ++i){
            int lin = tid + i*256;          // 0..1023
            int r = lin >> 4, c4 = lin & 15;
            float4 v = *(const float4*)&W[(size_t)(r0+r)*DD + c0 + c4*4];
            Ts[r][c4*4+0] = v.x; Ts[r][c4*4+1] = v.y;
            Ts[r][c4*4+2] = v.z; Ts[r][c4*4+3] = v.w;
        }
        __syncthreads();
        // transposed store as ushort4 (4 iters x 256 thr x 8B)
        #pragma unroll
        for (int i = 0; i < 4; ++i){
            int lin = tid + i*256;          // 0..1023
            int r = lin >> 4, c4 = lin & 15;
            ushort4 o;
            o.x = f2bfbits(Ts[c4*4+0][r]);
            o.y = f2bfbits(Ts[c4*4+1][r]);
            o.z = f2bfbits(Ts[c4*4+2][r]);
            o.w = f2bfbits(Ts[c4*4+3][r]);
            *(ushort4*)&WT[(size_t)(c0+r)*DD + r0 + c4*4] = o;
        }
    } else {
        __shared__ float red[4];
        const int row = id - 1536;
        float4 xv = ((const float4*)(pa.x + (size_t)row*DD))[tid];
        float v[4] = {xv.x, xv.y, xv.z, xv.w};
        float s = v[0]+v[1]+v[2]+v[3];
        #pragma unroll
        for (int off = 32; off > 0; off >>= 1) s += __shfl_down(s, off, 64);
        if ((tid & 63) == 0) red[tid >> 6] = s;
        __syncthreads();
        const float mean = (red[0]+red[1]+red[2]+red[3]) * (1.0f/DD);
        __syncthreads();
        float q = 0.f;
        #pragma unroll
        for (int i = 0; i < 4; ++i){ float d = v[i]-mean; q += d*d; }
        #pragma unroll
        for (int off = 32; off > 0; off >>= 1) q += __shfl_down(q, off, 64);
        if ((tid & 63) == 0) red[tid >> 6] = q;
        __syncthreads();
        const float var = (red[0]+red[1]+red[2]+red[3]) * (1.0f/(DD-1));
        const float inv = 1.0f/(sqrtf(var) + LN_EPS);
        float4 g4 = ((const float4*)pa.g1)[tid];
        float4 b4 = ((const float4*)pa.be1)[tid];
        ushort4 o;
        o.x = f2bfbits(g4.x*(v[0]-mean)*inv + b4.x);
        o.y = f2bfbits(g4.y*(v[1]-mean)*inv + b4.y);
        o.z = f2bfbits(g4.z*(v[2]-mean)*inv + b4.z);
        o.w = f2bfbits(g4.w*(v[3]-mean)*inv + b4.w);
        ((ushort4*)(pa.ln + (size_t)row*DD))[tid] = o;
    }
}

// ---------- LayerNorm: fp32 in -> bf16 out (standalone, for LN2) ----------
__global__ __launch_bounds__(256)
void ln_f32(const float* __restrict__ x, const float* __restrict__ gamma,
            const float* __restrict__ beta, unsigned short* __restrict__ out)
{
    __shared__ float red[4];
    const int row = blockIdx.x;
    const int tid = threadIdx.x;
    float4 xv = ((const float4*)(x + (size_t)row*DD))[tid];
    float v[4] = {xv.x, xv.y, xv.z, xv.w};
    float s = v[0]+v[1]+v[2]+v[3];
    #pragma unroll
    for (int off = 32; off > 0; off >>= 1) s += __shfl_down(s, off, 64);
    if ((tid & 63) == 0) red[tid >> 6] = s;
    __syncthreads();
    const float mean = (red[0]+red[1]+red[2]+red[3]) * (1.0f/DD);
    __syncthreads();
    float q = 0.f;
    #pragma unroll
    for (int i = 0; i < 4; ++i){ float d = v[i]-mean; q += d*d; }
    #pragma unroll
    for (int off = 32; off > 0; off >>= 1) q += __shfl_down(q, off, 64);
    if ((tid & 63) == 0) red[tid >> 6] = q;
    __syncthreads();
    const float var = (red[0]+red[1]+red[2]+red[3]) * (1.0f/(DD-1));
    const float inv = 1.0f/(sqrtf(var) + LN_EPS);
    float4 g4 = ((const float4*)gamma)[tid];
    float4 b4 = ((const float4*)beta)[tid];
    ushort4 o;
    o.x = f2bfbits(g4.x*(v[0]-mean)*inv + b4.x);
    o.y = f2bfbits(g4.y*(v[1]-mean)*inv + b4.y);
    o.z = f2bfbits(g4.z*(v[2]-mean)*inv + b4.z);
    o.w = f2bfbits(g4.w*(v[3]-mean)*inv + b4.w);
    ((ushort4*)(out + (size_t)row*DD))[tid] = o;
}

// =========== double-buffered MFMA main loop (iso-occupancy pipelining) ===========
// 128x128 tile, BK=64, 4 waves 2x2. TWO static buffer pairs (64 KB -> still
// 2 blocks/CU). Counted vmcnt(8): each tile's loads get a full compute phase
// to land. Best measured structure for this problem's K=1024 geometry
// (~850 TF; 8-phase/256-tile ports regressed in R2/R3/R4/R11 — short K-loop
// + occupancy loss eat the interleave gain).
template<bool PACKED>
__device__ __forceinline__ void mfma_db(
    const unsigned short* const ga[4], const unsigned short* const gb[4],
    const int* pw, const unsigned short* zpad, const int NT,
    f32x4 acc[4][4], const int wave, const int lane,
    unsigned short (&As0)[8192], unsigned short (&Bs0)[8192],
    unsigned short (&As1)[8192], unsigned short (&Bs1)[8192])
{
    const int quad = lane >> 4, l15 = lane & 15;
    const int wm = ((wave >> 1) & 1) * 64, wn = (wave & 1) * 64;

    auto stage = [&](unsigned short (&Ab)[8192], unsigned short (&Bb)[8192], const int koff){
        #pragma unroll
        for (int c = 0; c < 4; ++c){
            const unsigned short* gp = ga[c] + koff;
            if constexpr (PACKED) { if (koff >= pw[c]) gp = zpad; }
            gl_lds(gp, &Ab[(wave*4+c)*512]);
            gl_lds(gb[c] + koff, &Bb[(wave*4+c)*512]);
        }
    };
    auto compute = [&](unsigned short (&Ab)[8192], unsigned short (&Bb)[8192]){
        #pragma unroll
        for (int kk = 0; kk < 2; ++kk){
            bf16x8 af[4], bfr[4];
            #pragma unroll
            for (int t = 0; t < 4; ++t){
                const int ra = wm + t*16 + l15, rb = wn + t*16 + l15, gi = kk*4 + quad;
                af[t]  = *(const bf16x8*)&Ab[ra*64 + (((gi + ra) & 7) << 3)];
                bfr[t] = *(const bf16x8*)&Bb[rb*64 + (((gi + rb) & 7) << 3)];
            }
            #pragma unroll
            for (int i = 0; i < 4; ++i)
                #pragma unroll
                for (int j = 0; j < 4; ++j)
                    acc[i][j] = __builtin_amdgcn_mfma_f32_16x16x32_bf16(af[i], bfr[j], acc[i][j], 0, 0, 0);
        }
    };

    stage(As0, Bs0, 0);
    const int half = NT >> 1;
    for (int i = 0; i < half; ++i){
        stage(As1, Bs1, (2*i + 1) << 6);
        asm volatile("s_waitcnt vmcnt(8)" ::: "memory");   // buf0 landed; buf1 in flight
        __builtin_amdgcn_s_barrier();
        __builtin_amdgcn_sched_barrier(0);
        compute(As0, Bs0);
        __builtin_amdgcn_s_barrier();                      // buf0 readers drained
        if (i + 1 < half){
            stage(As0, Bs0, (2*i + 2) << 6);
            asm volatile("s_waitcnt vmcnt(8)" ::: "memory");   // buf1 landed
        } else {
            asm volatile("s_waitcnt vmcnt(0)" ::: "memory");   // tail drain
        }
        __builtin_amdgcn_s_barrier();
        __builtin_amdgcn_sched_barrier(0);
        compute(As1, Bs1);
        __builtin_amdgcn_s_barrier();                      // buf1 readers drained
    }
}

__device__ __forceinline__ void mk_chunks(const unsigned short* base, size_t ld, int r0,
                                          int wave, int lane, const unsigned short* g[4]){
    #pragma unroll
    for (int c = 0; c < 4; ++c){
        const int mr = (wave*4 + c)*8 + (lane >> 3);
        const int gk = ((lane & 7) - mr) & 7;
        g[c] = base + (size_t)(r0 + mr)*ld + gk*8;
    }
}

#define DECL_DB \
    __shared__ unsigned short As0[8192]; \
    __shared__ unsigned short Bs0[8192]; \
    __shared__ unsigned short As1[8192]; \
    __shared__ unsigned short Bs1[8192];

// =========== GEMM core wrapper (double-buffered) ===========
template<bool RELU, bool RES, bool OUTF, bool BIAS_M>
__device__ __forceinline__ void gemm_core(
    const unsigned short* __restrict__ A, const unsigned short* __restrict__ B,
    const float* __restrict__ bias, const float* __restrict__ resF,
    unsigned short* __restrict__ outB, float* __restrict__ outF,
    const int N, const int K, const int lda, const int ldb,
    const int m0, const int n0,
    unsigned short (&As0)[8192], unsigned short (&Bs0)[8192],
    unsigned short (&As1)[8192], unsigned short (&Bs1)[8192])
{
    const int tid = threadIdx.x, lane = tid & 63, wave = tid >> 6;
    const int wm = ((wave >> 1) & 1) * 64, wn = (wave & 1) * 64;
    const int quad = lane >> 4, l15 = lane & 15;
    const unsigned short* ga[4]; const unsigned short* gb[4];
    mk_chunks(A, lda, m0, wave, lane, ga);
    mk_chunks(B, ldb, n0, wave, lane, gb);
    f32x4 acc[4][4] = {};
    mfma_db<false>(ga, gb, nullptr, nullptr, K >> 6, acc, wave, lane, As0, Bs0, As1, Bs1);
    #pragma unroll
    for (int i = 0; i < 4; ++i){
        #pragma unroll
        for (int r = 0; r < 4; ++r){
            const int m = m0 + wm + i*16 + quad*4 + r;
            const float bm = BIAS_M ? bias[m] : 0.f;
            #pragma unroll
            for (int j = 0; j < 4; ++j){
                const int n = n0 + wn + j*16 + l15;
                float v = acc[i][j][r] + (BIAS_M ? bm : bias[n]);
                if constexpr (RELU) v = fmaxf(v, 0.f);
                if constexpr (RES) v += resF[(size_t)m*N + n];
                if constexpr (OUTF) outF[(size_t)m*N + n] = v;
                else outB[(size_t)m*N + n] = f2bfbits(v);
            }
        }
    }
}

// generic single GEMM (double-buffered)
template<bool RELU, bool RES, bool OUTF, bool BIAS_M>
__global__ __launch_bounds__(256)
void gemm_mfma(const unsigned short* __restrict__ A, const unsigned short* __restrict__ B,
               const float* __restrict__ bias, const float* __restrict__ resF,
               unsigned short* __restrict__ outB, float* __restrict__ outF,
               const int N, const int K, const int lda, const int ldb)
{
    DECL_DB
    const int3 b = xcd_swz();
    gemm_core<RELU,RES,OUTF,BIAS_M>(A, B, bias, resF, outB, outF, N, K, lda, ldb,
                                    b.y*128, b.x*128, As0, Bs0, As1, Bs1);
}

// ---------- fused Q/K/VT projections: 1536 uniform tiles in ONE launch ----------
// db core + reordered VT ids (m0 fastest): best cell of the {buffering x
// VT-order} 2x2 (R10: 60.8us, MfmaUtil 35%, FETCH 48MB).
__global__ __launch_bounds__(256)
void proj_fused(const unsigned short* __restrict__ LN,
                const unsigned short* __restrict__ WqT, const unsigned short* __restrict__ WkT,
                const unsigned short* __restrict__ WvT,
                const float* __restrict__ bq, const float* __restrict__ bk,
                const float* __restrict__ bv,
                unsigned short* __restrict__ Qw, unsigned short* __restrict__ Kw,
                unsigned short* __restrict__ VTw)
{
    DECL_DB
    const int lin = blockIdx.x;                    // 1536
    const int id = (lin & 7) * 192 + (lin >> 3);   // chunked XCD swizzle
    if (id < 1024){
        const bool isK = (id >= 512);
        const int q = id & 511;
        const int n0 = (q & 7) * 128, m0 = (q >> 3) * 128;   // n over DD, m over MM
        gemm_core<false,false,false,false>(LN, isK ? WkT : WqT, isK ? bk : bq, nullptr,
                                           isK ? Kw : Qw, nullptr, DD, DD, DD, DD,
                                           m0, n0, As0, Bs0, As1, Bs1);
    } else {
        const int q = id - 1024;
        const int m0 = (q & 7) * 128, n0 = (q >> 3) * 128;   // m over DD, n over MM
        gemm_core<false,false,false,true>(WvT, LN, bv, nullptr, VTw, nullptr,
                                          MM, DD, DD, DD, m0, n0, As0, Bs0, As1, Bs1);
    }
}

// ---------- scores: packed P = exp(Q*K^T * scale), causal, UNNORMALIZED ----------
__global__ __launch_bounds__(256)
void scores_mfma(const unsigned short* __restrict__ Qb, const unsigned short* __restrict__ Kb,
                 unsigned short* __restrict__ Pb, float* __restrict__ Lf, const float scale)
{
    const int lin = blockIdx.x;                    // 544 = 4 * 136
    const int id = (lin & 7) * 68 + (lin >> 3);    // chunked XCD swizzle
    const int z = id / 136;
    const int idx = id - z * 136;
    int y = (int)((sqrtf(8.f * (float)idx + 1.f) - 1.f) * 0.5f);
    while ((y + 1) * (y + 2) / 2 <= idx) ++y;      // guard float error
    while (y * (y + 1) / 2 > idx) --y;
    const int x = idx - y * (y + 1) / 2;           // x <= y
    const int s0 = y * 128, t0 = x * 128;

    const unsigned short* Q  = Qb + (size_t)z*SD;
    const unsigned short* Km = Kb + (size_t)z*SD;
    unsigned short* P        = Pb + (size_t)z*PPB;
    float* L                 = Lf + (size_t)z*SS;
    DECL_DB
    const int tid = threadIdx.x, lane = tid & 63, wave = tid >> 6;
    const int wm = ((wave >> 1) & 1) * 64, wn = (wave & 1) * 64;
    const int quad = lane >> 4, l15 = lane & 15;
    const unsigned short* ga[4]; const unsigned short* gb[4];
    mk_chunks(Q,  DD, s0, wave, lane, ga);
    mk_chunks(Km, DD, t0, wave, lane, gb);
    f32x4 acc[4][4] = {};
    mfma_db<false>(ga, gb, nullptr, nullptr, DD >> 6, acc, wave, lane, As0, Bs0, As1, Bs1);

    #pragma unroll
    for (int i = 0; i < 4; ++i){
        #pragma unroll
        for (int r = 0; r < 4; ++r){
            const int s = s0 + wm + i*16 + quad*4 + r;
            const int width = rowWidth(s);
            unsigned short* pr = P + rowOff(s);
            float psum = 0.f;
            if (t0 + wn < width){                    // 64-chunk uniform in/out
                #pragma unroll
                for (int j = 0; j < 4; ++j){
                    const int t = t0 + wn + j*16 + l15;
                    const float e = (t <= s) ? __expf(acc[i][j][r] * scale) : 0.f;
                    pr[t] = f2bfbits(e);
                    psum += e;
                }
                #pragma unroll
                for (int off = 8; off > 0; off >>= 1) psum += __shfl_xor(psum, off, 64);
                if (l15 == 0) atomicAdd(&L[s], psum);
            }
        }
    }
}

// ---------- ctx = (P @ V) / l ; A=packed unnormalized P, B=VT[d][tok] ----------
// Causal-balance remap: y' = (z>=2) ? 15-y : y (complementary co-resident pairs).
__global__ __launch_bounds__(256)
void pv_mfma(const unsigned short* __restrict__ Pb, const unsigned short* __restrict__ VT,
             unsigned short* __restrict__ Cb, const unsigned short* __restrict__ zpad,
             const float* __restrict__ Lf)
{
    const int yr = blockIdx.y;
    const int y  = (blockIdx.z >= 2) ? (15 - yr) : yr;
    const int s0 = y*128, n0 = blockIdx.x*128;
    const unsigned short* P = Pb + (size_t)blockIdx.z*PPB;
    unsigned short* C       = Cb + (size_t)blockIdx.z*SD;
    const float* L          = Lf + (size_t)blockIdx.z*SS;
    const int bcol = blockIdx.z*SS;
    DECL_DB
    const int tid = threadIdx.x, lane = tid & 63, wave = tid >> 6;
    const int wm = ((wave >> 1) & 1) * 64, wn = (wave & 1) * 64;
    const int quad = lane >> 4, l15 = lane & 15;
    const unsigned short* ga[4]; const unsigned short* gb[4]; int pw[4];
    #pragma unroll
    for (int c = 0; c < 4; ++c){
        const int mr = (wave*4 + c)*8 + (lane >> 3);
        const int gk = ((lane & 7) - mr) & 7;
        const int s = s0 + mr;
        pw[c] = rowWidth(s) - gk*8;                 // chunk valid iff koff < pw
        ga[c] = P + rowOff(s) + gk*8;
    }
    mk_chunks(VT + bcol, MM, n0, wave, lane, gb);
    f32x4 acc[4][4] = {};
    const int NT = (s0 >> 6) + 2;                   // 2y+2, even
    mfma_db<true>(ga, gb, pw, zpad, NT, acc, wave, lane, As0, Bs0, As1, Bs1);

    #pragma unroll
    for (int i = 0; i < 4; ++i){
        #pragma unroll
        for (int r = 0; r < 4; ++r){
            const int s = s0 + wm + i*16 + quad*4 + r;
            const float linv = 1.0f / L[s];
            #pragma unroll
            for (int j = 0; j < 4; ++j){
                const int n = n0 + wn + j*16 + l15;
                C[(size_t)s*DD + n] = f2bfbits(acc[i][j][r] * linv);
            }
        }
    }
}

extern "C" void kernel_launch(void* const* d_in, const int* in_sizes, int n_in,
                              void* d_out, int out_size, void* d_ws, size_t ws_size,
                              hipStream_t stream)
{
    (void)in_sizes; (void)n_in; (void)out_size;
    const float* x   = (const float*)d_in[0];
    const float* bq  = (const float*)d_in[2];
    const float* bk  = (const float*)d_in[4];
    const float* bv  = (const float*)d_in[6];
    const float* bo  = (const float*)d_in[8];
    const float* b1  = (const float*)d_in[10];
    const float* b2  = (const float*)d_in[12];
    const float* g1  = (const float*)d_in[13];
    const float* be1 = (const float*)d_in[14];
    const float* g2  = (const float*)d_in[15];
    const float* be2 = (const float*)d_in[16];
    float* outf = (float*)d_out;

    if (ws_size < (size_t)REQ_WS){
        sentinel_kernel<<<dim3((unsigned)(MD/256)), dim3(256), 0, stream>>>(outf, 1.0e9f);
        return;
    }

    unsigned short* wsb = (unsigned short*)d_ws;
    unsigned short* Qw  = wsb;                 // -> ctx
    unsigned short* Kw  = wsb + MD;            // \ -> Hf (fp32 spans K+VT)
    unsigned short* VTw = wsb + 2*MD;          // /
    unsigned short* Pw  = wsb + 3*MD;          // packed P -> mid
    unsigned short* WT  = wsb + WT_OFF;
    unsigned short* ZP  = wsb + ZP_OFF;
    float*          Lf  = (float*)(wsb + LF_OFF);
    float*          Hf  = (float*)Kw;
    unsigned short* CTX = Qw;
    unsigned short* MIDw= Pw;
    unsigned short* LN  = (unsigned short*)d_out;   // LN1/LN2 scratch in d_out

    PrepArgs pa;
    static const int widx[6] = {1,3,5,7,9,11};
    for (int i = 0; i < 6; ++i){
        pa.wp.w[i] = (const float*)d_in[widx[i]];
        pa.wp.o[i] = WT + (size_t)i*DD*DD;
    }
    pa.wp.zp = ZP;
    pa.wp.lf = Lf;
    pa.x = x; pa.g1 = g1; pa.be1 = be1; pa.ln = LN;
    unsigned short* WqT = pa.wp.o[0]; unsigned short* WkT = pa.wp.o[1];
    unsigned short* WvT = pa.wp.o[2]; unsigned short* WoT = pa.wp.o[3];
    unsigned short* W1T = pa.wp.o[4]; unsigned short* W2T = pa.wp.o[5];

    const dim3 blk(256);
    const float scale = 1.0f / sqrtf((float)SS);
    const dim3 gA(DD/128, MM/128);    // (8,64)

    // fused wtrans + LN1 (independent streams, one launch)
    prep<<<dim3(1536 + MM), blk, 0, stream>>>(pa);
    // fused Q + K + VT projections (1536 uniform tiles, one launch)
    proj_fused<<<dim3(1536), blk, 0, stream>>>(LN, WqT, WkT, WvT, bq, bk, bv, Qw, Kw, VTw);
    // attention: fused exp-scores (+row sums, triangular-packed) then PV (/rowsum)
    scores_mfma<<<dim3(544), blk, 0, stream>>>(Qw, Kw, Pw, Lf, scale);
    pv_mfma<<<dim3(DD/128, SS/128, BB), blk, 0, stream>>>(Pw, VTw, CTX, ZP, Lf);
    // h = ctx*WoT^T + bo + x (fp32)
    gemm_mfma<false,true,true,false><<<gA, blk, 0, stream>>>(CTX, WoT, bo, x, nullptr, Hf, DD, DD, DD, DD);
    ln_f32<<<dim3(MM), blk, 0, stream>>>(Hf, g2, be2, LN);
    // mid = relu(LN*W1T^T + b1)
    gemm_mfma<true,false,false,false><<<gA, blk, 0, stream>>>(LN, W1T, b1, nullptr, MIDw, nullptr, DD, DD, DD, DD);
    // out = mid*W2T^T + b2 + h
    gemm_mfma<false,true,true,false><<<gA, blk, 0, stream>>>(MIDw, W2T, b2, Hf, nullptr, outf, DD, DD, DD, DD);
}

// Round 14
// 326.970 us; speedup vs baseline: 1.0505x; 1.0471x over previous
//
#include <hip/hip_runtime.h>
#include <math.h>

#define BB 4
#define SS 2048
#define DD 1024
#define MM (BB*SS)                   // 8192
#define SD ((size_t)SS*DD)
#define MD ((size_t)MM*DD)           // 8,388,608
#define PPB ((size_t)2162688)        // packed P elems per batch

// ws (bf16 elems): Q@0 | K@MD (-> Hb bf16) | VT@2MD | P@3MD (4*PPB) | WT (6*DD*DD) | zpad(16) | L (8192 f32)
#define WT_OFF (3*MD + 4*PPB)
#define ZP_OFF (WT_OFF + 6*(size_t)DD*DD)
#define LF_OFF (ZP_OFF + 16)
#define REQ_WS ((LF_OFF + 16384) * 2)

constexpr float LN_EPS = 1e-6f;

typedef __attribute__((ext_vector_type(8))) __bf16 bf16x8;
typedef __attribute__((ext_vector_type(4))) float f32x4;

__device__ __forceinline__ unsigned short f2bfbits(float f){
    unsigned u = __float_as_uint(f);
    u += 0x7FFFu + ((u >> 16) & 1u);   // RNE
    return (unsigned short)(u >> 16);
}
__device__ __forceinline__ float bf2f(unsigned short u){
    return __uint_as_float(((unsigned)u) << 16);
}
__device__ __forceinline__ int rowWidth(int s){ return ((s >> 6) + 1) << 6; }
__device__ __forceinline__ size_t rowOff(int s){
    int g = s >> 6;
    return (size_t)4096 * (size_t)((g * (g + 1)) >> 1) + (size_t)(s & 63) * (size_t)((g + 1) << 6);
}
// async global->LDS, 16B per lane; LDS dest = wave-uniform base + lane*16
__device__ __forceinline__ void gl_lds(const unsigned short* g, unsigned short* l){
    __builtin_amdgcn_global_load_lds(
        (const __attribute__((address_space(1))) unsigned int*)g,
        (__attribute__((address_space(3))) unsigned int*)l, 16, 0, 0);
}

// XCD-aware bijective block swizzle (T1) — uniform-work launches only.
__device__ __forceinline__ int3 xcd_swz(){
    const int gx = gridDim.x, gy = gridDim.y, gz = gridDim.z;
    const int n = gx * gy * gz;
    int lin = blockIdx.x + gx * (blockIdx.y + gy * blockIdx.z);
    const int cpx = n >> 3;                 // n % 8 == 0 for all swizzled launches
    lin = (lin & 7) * cpx + (lin >> 3);     // bijection: XCD (lin&7) owns chunk
    int3 r;
    r.x = lin % gx; lin /= gx;
    r.y = lin % gy;
    r.z = lin / gy;
    return r;
}

__global__ __launch_bounds__(256)
void sentinel_kernel(float* __restrict__ out, const float val){
    out[(size_t)blockIdx.x * 256 + threadIdx.x] = val;
}

// ---------- prep: fused {weight transpose + zpad/L zero} and {LayerNorm1} ----------
// wtrans path vectorized (G13): float4 loads (16B/lane), ushort4 stores (8B/lane).
struct WPack { const float* w[6]; unsigned short* o[6]; unsigned short* zp; float* lf; };
struct PrepArgs { WPack wp; const float* x; const float* g1; const float* be1;
                  unsigned short* ln; };
__global__ __launch_bounds__(256)
void prep(PrepArgs pa)
{
    const int id = blockIdx.x;
    const int tid = threadIdx.x;
    if (id < 1536){
        __shared__ float Ts[64][65];
        const int z = id >> 8, rem = id & 255;
        const int yy = rem >> 4, xx = rem & 15;
        const float* W = pa.wp.w[z];
        unsigned short* WT = pa.wp.o[z];
        const int r0 = yy*64, c0 = xx*64;
        if (id == 0 && tid < 16) pa.wp.zp[tid] = 0;
        if (id < 16){                       // zero L[8192] f32
            float2 z2 = {0.f, 0.f};
            ((float2*)pa.wp.lf)[id*256 + tid] = z2;
        }
        // load 64x64 f32 tile as float4 (4 iters x 256 thr x 16B)
        #pragma unroll
        for (int i = 0; i < 4; ++i){
            int lin = tid + i*256;          // 0..1023
            int r = lin >> 4, c4 = lin & 15;
            float4 v = *(const float4*)&W[(size_t)(r0+r)*DD + c0 + c4*4];
            Ts[r][c4*4+0] = v.x; Ts[r][c4*4+1] = v.y;
            Ts[r][c4*4+2] = v.z; Ts[r][c4*4+3] = v.w;
        }
        __syncthreads();
        // transposed store as ushort4 (4 iters x 256 thr x 8B)
        #pragma unroll
        for (int i = 0; i < 4; ++i){
            int lin = tid + i*256;          // 0..1023
            int r = lin >> 4, c4 = lin & 15;
            ushort4 o;
            o.x = f2bfbits(Ts[c4*4+0][r]);
            o.y = f2bfbits(Ts[c4*4+1][r]);
            o.z = f2bfbits(Ts[c4*4+2][r]);
            o.w = f2bfbits(Ts[c4*4+3][r]);
            *(ushort4*)&WT[(size_t)(c0+r)*DD + r0 + c4*4] = o;
        }
    } else {
        __shared__ float red[4];
        const int row = id - 1536;
        float4 xv = ((const float4*)(pa.x + (size_t)row*DD))[tid];
        float v[4] = {xv.x, xv.y, xv.z, xv.w};
        float s = v[0]+v[1]+v[2]+v[3];
        #pragma unroll
        for (int off = 32; off > 0; off >>= 1) s += __shfl_down(s, off, 64);
        if ((tid & 63) == 0) red[tid >> 6] = s;
        __syncthreads();
        const float mean = (red[0]+red[1]+red[2]+red[3]) * (1.0f/DD);
        __syncthreads();
        float q = 0.f;
        #pragma unroll
        for (int i = 0; i < 4; ++i){ float d = v[i]-mean; q += d*d; }
        #pragma unroll
        for (int off = 32; off > 0; off >>= 1) q += __shfl_down(q, off, 64);
        if ((tid & 63) == 0) red[tid >> 6] = q;
        __syncthreads();
        const float var = (red[0]+red[1]+red[2]+red[3]) * (1.0f/(DD-1));
        const float inv = 1.0f/(sqrtf(var) + LN_EPS);
        float4 g4 = ((const float4*)pa.g1)[tid];
        float4 b4 = ((const float4*)pa.be1)[tid];
        ushort4 o;
        o.x = f2bfbits(g4.x*(v[0]-mean)*inv + b4.x);
        o.y = f2bfbits(g4.y*(v[1]-mean)*inv + b4.y);
        o.z = f2bfbits(g4.z*(v[2]-mean)*inv + b4.z);
        o.w = f2bfbits(g4.w*(v[3]-mean)*inv + b4.w);
        ((ushort4*)(pa.ln + (size_t)row*DD))[tid] = o;
    }
}

// ---------- LayerNorm: bf16 in -> bf16 out (LN2; h stored bf16) ----------
__global__ __launch_bounds__(256)
void ln_bf16(const unsigned short* __restrict__ x, const float* __restrict__ gamma,
             const float* __restrict__ beta, unsigned short* __restrict__ out)
{
    __shared__ float red[4];
    const int row = blockIdx.x;
    const int tid = threadIdx.x;
    ushort4 xv = ((const ushort4*)(x + (size_t)row*DD))[tid];
    float v[4] = {bf2f(xv.x), bf2f(xv.y), bf2f(xv.z), bf2f(xv.w)};
    float s = v[0]+v[1]+v[2]+v[3];
    #pragma unroll
    for (int off = 32; off > 0; off >>= 1) s += __shfl_down(s, off, 64);
    if ((tid & 63) == 0) red[tid >> 6] = s;
    __syncthreads();
    const float mean = (red[0]+red[1]+red[2]+red[3]) * (1.0f/DD);
    __syncthreads();
    float q = 0.f;
    #pragma unroll
    for (int i = 0; i < 4; ++i){ float d = v[i]-mean; q += d*d; }
    #pragma unroll
    for (int off = 32; off > 0; off >>= 1) q += __shfl_down(q, off, 64);
    if ((tid & 63) == 0) red[tid >> 6] = q;
    __syncthreads();
    const float var = (red[0]+red[1]+red[2]+red[3]) * (1.0f/(DD-1));
    const float inv = 1.0f/(sqrtf(var) + LN_EPS);
    float4 g4 = ((const float4*)gamma)[tid];
    float4 b4 = ((const float4*)beta)[tid];
    ushort4 o;
    o.x = f2bfbits(g4.x*(v[0]-mean)*inv + b4.x);
    o.y = f2bfbits(g4.y*(v[1]-mean)*inv + b4.y);
    o.z = f2bfbits(g4.z*(v[2]-mean)*inv + b4.z);
    o.w = f2bfbits(g4.w*(v[3]-mean)*inv + b4.w);
    ((ushort4*)(out + (size_t)row*DD))[tid] = o;
}

// =========== double-buffered MFMA main loop (iso-occupancy pipelining) ===========
// 128x128 tile, BK=64, 4 waves 2x2. TWO static buffer pairs (64 KB -> still
// 2 blocks/CU). Counted vmcnt(8). Best measured structure for this problem's
// K=1024 geometry (~850 TF; 8-phase/256-tile ports regressed R2/R3/R4/R11).
template<bool PACKED>
__device__ __forceinline__ void mfma_db(
    const unsigned short* const ga[4], const unsigned short* const gb[4],
    const int* pw, const unsigned short* zpad, const int NT,
    f32x4 acc[4][4], const int wave, const int lane,
    unsigned short (&As0)[8192], unsigned short (&Bs0)[8192],
    unsigned short (&As1)[8192], unsigned short (&Bs1)[8192])
{
    const int quad = lane >> 4, l15 = lane & 15;
    const int wm = ((wave >> 1) & 1) * 64, wn = (wave & 1) * 64;

    auto stage = [&](unsigned short (&Ab)[8192], unsigned short (&Bb)[8192], const int koff){
        #pragma unroll
        for (int c = 0; c < 4; ++c){
            const unsigned short* gp = ga[c] + koff;
            if constexpr (PACKED) { if (koff >= pw[c]) gp = zpad; }
            gl_lds(gp, &Ab[(wave*4+c)*512]);
            gl_lds(gb[c] + koff, &Bb[(wave*4+c)*512]);
        }
    };
    auto compute = [&](unsigned short (&Ab)[8192], unsigned short (&Bb)[8192]){
        #pragma unroll
        for (int kk = 0; kk < 2; ++kk){
            bf16x8 af[4], bfr[4];
            #pragma unroll
            for (int t = 0; t < 4; ++t){
                const int ra = wm + t*16 + l15, rb = wn + t*16 + l15, gi = kk*4 + quad;
                af[t]  = *(const bf16x8*)&Ab[ra*64 + (((gi + ra) & 7) << 3)];
                bfr[t] = *(const bf16x8*)&Bb[rb*64 + (((gi + rb) & 7) << 3)];
            }
            #pragma unroll
            for (int i = 0; i < 4; ++i)
                #pragma unroll
                for (int j = 0; j < 4; ++j)
                    acc[i][j] = __builtin_amdgcn_mfma_f32_16x16x32_bf16(af[i], bfr[j], acc[i][j], 0, 0, 0);
        }
    };

    stage(As0, Bs0, 0);
    const int half = NT >> 1;
    for (int i = 0; i < half; ++i){
        stage(As1, Bs1, (2*i + 1) << 6);
        asm volatile("s_waitcnt vmcnt(8)" ::: "memory");   // buf0 landed; buf1 in flight
        __builtin_amdgcn_s_barrier();
        __builtin_amdgcn_sched_barrier(0);
        compute(As0, Bs0);
        __builtin_amdgcn_s_barrier();                      // buf0 readers drained
        if (i + 1 < half){
            stage(As0, Bs0, (2*i + 2) << 6);
            asm volatile("s_waitcnt vmcnt(8)" ::: "memory");   // buf1 landed
        } else {
            asm volatile("s_waitcnt vmcnt(0)" ::: "memory");   // tail drain
        }
        __builtin_amdgcn_s_barrier();
        __builtin_amdgcn_sched_barrier(0);
        compute(As1, Bs1);
        __builtin_amdgcn_s_barrier();                      // buf1 readers drained
    }
}

__device__ __forceinline__ void mk_chunks(const unsigned short* base, size_t ld, int r0,
                                          int wave, int lane, const unsigned short* g[4]){
    #pragma unroll
    for (int c = 0; c < 4; ++c){
        const int mr = (wave*4 + c)*8 + (lane >> 3);
        const int gk = ((lane & 7) - mr) & 7;
        g[c] = base + (size_t)(r0 + mr)*ld + gk*8;
    }
}

#define DECL_DB \
    __shared__ unsigned short As0[8192]; \
    __shared__ unsigned short Bs0[8192]; \
    __shared__ unsigned short As1[8192]; \
    __shared__ unsigned short Bs1[8192];

// =========== GEMM core wrapper (double-buffered) ===========
// RES: += fp32 residual resF. RESB: += bf16 residual resB (h path).
template<bool RELU, bool RES, bool RESB, bool OUTF, bool BIAS_M>
__device__ __forceinline__ void gemm_core(
    const unsigned short* __restrict__ A, const unsigned short* __restrict__ B,
    const float* __restrict__ bias, const float* __restrict__ resF,
    const unsigned short* __restrict__ resB,
    unsigned short* __restrict__ outB, float* __restrict__ outF,
    const int N, const int K, const int lda, const int ldb,
    const int m0, const int n0,
    unsigned short (&As0)[8192], unsigned short (&Bs0)[8192],
    unsigned short (&As1)[8192], unsigned short (&Bs1)[8192])
{
    const int tid = threadIdx.x, lane = tid & 63, wave = tid >> 6;
    const int wm = ((wave >> 1) & 1) * 64, wn = (wave & 1) * 64;
    const int quad = lane >> 4, l15 = lane & 15;
    const unsigned short* ga[4]; const unsigned short* gb[4];
    mk_chunks(A, lda, m0, wave, lane, ga);
    mk_chunks(B, ldb, n0, wave, lane, gb);
    f32x4 acc[4][4] = {};
    mfma_db<false>(ga, gb, nullptr, nullptr, K >> 6, acc, wave, lane, As0, Bs0, As1, Bs1);
    #pragma unroll
    for (int i = 0; i < 4; ++i){
        #pragma unroll
        for (int r = 0; r < 4; ++r){
            const int m = m0 + wm + i*16 + quad*4 + r;
            const float bm = BIAS_M ? bias[m] : 0.f;
            #pragma unroll
            for (int j = 0; j < 4; ++j){
                const int n = n0 + wn + j*16 + l15;
                float v = acc[i][j][r] + (BIAS_M ? bm : bias[n]);
                if constexpr (RELU) v = fmaxf(v, 0.f);
                if constexpr (RES)  v += resF[(size_t)m*N + n];
                if constexpr (RESB) v += bf2f(resB[(size_t)m*N + n]);
                if constexpr (OUTF) outF[(size_t)m*N + n] = v;
                else outB[(size_t)m*N + n] = f2bfbits(v);
            }
        }
    }
}

// generic single GEMM (double-buffered)
template<bool RELU, bool RES, bool RESB, bool OUTF, bool BIAS_M>
__global__ __launch_bounds__(256)
void gemm_mfma(const unsigned short* __restrict__ A, const unsigned short* __restrict__ B,
               const float* __restrict__ bias, const float* __restrict__ resF,
               const unsigned short* __restrict__ resB,
               unsigned short* __restrict__ outB, float* __restrict__ outF,
               const int N, const int K, const int lda, const int ldb)
{
    DECL_DB
    const int3 b = xcd_swz();
    gemm_core<RELU,RES,RESB,OUTF,BIAS_M>(A, B, bias, resF, resB, outB, outF,
                                         N, K, lda, ldb,
                                         b.y*128, b.x*128, As0, Bs0, As1, Bs1);
}

// ---------- fused Q/K/VT projections: 1536 uniform tiles in ONE launch ----------
// db core + reordered VT ids (m0 fastest): best cell of the {buffering x
// VT-order} 2x2 (R10: 60.8us, MfmaUtil 35%, FETCH 48MB).
__global__ __launch_bounds__(256)
void proj_fused(const unsigned short* __restrict__ LN,
                const unsigned short* __restrict__ WqT, const unsigned short* __restrict__ WkT,
                const unsigned short* __restrict__ WvT,
                const float* __restrict__ bq, const float* __restrict__ bk,
                const float* __restrict__ bv,
                unsigned short* __restrict__ Qw, unsigned short* __restrict__ Kw,
                unsigned short* __restrict__ VTw)
{
    DECL_DB
    const int lin = blockIdx.x;                    // 1536
    const int id = (lin & 7) * 192 + (lin >> 3);   // chunked XCD swizzle
    if (id < 1024){
        const bool isK = (id >= 512);
        const int q = id & 511;
        const int n0 = (q & 7) * 128, m0 = (q >> 3) * 128;   // n over DD, m over MM
        gemm_core<false,false,false,false,false>(LN, isK ? WkT : WqT, isK ? bk : bq,
                                                 nullptr, nullptr,
                                                 isK ? Kw : Qw, nullptr, DD, DD, DD, DD,
                                                 m0, n0, As0, Bs0, As1, Bs1);
    } else {
        const int q = id - 1024;
        const int m0 = (q & 7) * 128, n0 = (q >> 3) * 128;   // m over DD, n over MM
        gemm_core<false,false,false,false,true>(WvT, LN, bv, nullptr, nullptr,
                                                VTw, nullptr, MM, DD, DD, DD,
                                                m0, n0, As0, Bs0, As1, Bs1);
    }
}

// ---------- scores: packed P = exp(Q*K^T * scale), causal, UNNORMALIZED ----------
__global__ __launch_bounds__(256)
void scores_mfma(const unsigned short* __restrict__ Qb, const unsigned short* __restrict__ Kb,
                 unsigned short* __restrict__ Pb, float* __restrict__ Lf, const float scale)
{
    const int lin = blockIdx.x;                    // 544 = 4 * 136
    const int id = (lin & 7) * 68 + (lin >> 3);    // chunked XCD swizzle
    const int z = id / 136;
    const int idx = id - z * 136;
    int y = (int)((sqrtf(8.f * (float)idx + 1.f) - 1.f) * 0.5f);
    while ((y + 1) * (y + 2) / 2 <= idx) ++y;      // guard float error
    while (y * (y + 1) / 2 > idx) --y;
    const int x = idx - y * (y + 1) / 2;           // x <= y
    const int s0 = y * 128, t0 = x * 128;

    const unsigned short* Q  = Qb + (size_t)z*SD;
    const unsigned short* Km = Kb + (size_t)z*SD;
    unsigned short* P        = Pb + (size_t)z*PPB;
    float* L                 = Lf + (size_t)z*SS;
    DECL_DB
    const int tid = threadIdx.x, lane = tid & 63, wave = tid >> 6;
    const int wm = ((wave >> 1) & 1) * 64, wn = (wave & 1) * 64;
    const int quad = lane >> 4, l15 = lane & 15;
    const unsigned short* ga[4]; const unsigned short* gb[4];
    mk_chunks(Q,  DD, s0, wave, lane, ga);
    mk_chunks(Km, DD, t0, wave, lane, gb);
    f32x4 acc[4][4] = {};
    mfma_db<false>(ga, gb, nullptr, nullptr, DD >> 6, acc, wave, lane, As0, Bs0, As1, Bs1);

    #pragma unroll
    for (int i = 0; i < 4; ++i){
        #pragma unroll
        for (int r = 0; r < 4; ++r){
            const int s = s0 + wm + i*16 + quad*4 + r;
            const int width = rowWidth(s);
            unsigned short* pr = P + rowOff(s);
            float psum = 0.f;
            if (t0 + wn < width){                    // 64-chunk uniform in/out
                #pragma unroll
                for (int j = 0; j < 4; ++j){
                    const int t = t0 + wn + j*16 + l15;
                    const float e = (t <= s) ? __expf(acc[i][j][r] * scale) : 0.f;
                    pr[t] = f2bfbits(e);
                    psum += e;
                }
                #pragma unroll
                for (int off = 8; off > 0; off >>= 1) psum += __shfl_xor(psum, off, 64);
                if (l15 == 0) atomicAdd(&L[s], psum);
            }
        }
    }
}

// ---------- ctx = (P @ V) / l ; A=packed unnormalized P, B=VT[d][tok] ----------
// Causal-balance remap: y' = (z>=2) ? 15-y : y (complementary co-resident pairs).
__global__ __launch_bounds__(256)
void pv_mfma(const unsigned short* __restrict__ Pb, const unsigned short* __restrict__ VT,
             unsigned short* __restrict__ Cb, const unsigned short* __restrict__ zpad,
             const float* __restrict__ Lf)
{
    const int yr = blockIdx.y;
    const int y  = (blockIdx.z >= 2) ? (15 - yr) : yr;
    const int s0 = y*128, n0 = blockIdx.x*128;
    const unsigned short* P = Pb + (size_t)blockIdx.z*PPB;
    unsigned short* C       = Cb + (size_t)blockIdx.z*SD;
    const float* L          = Lf + (size_t)blockIdx.z*SS;
    const int bcol = blockIdx.z*SS;
    DECL_DB
    const int tid = threadIdx.x, lane = tid & 63, wave = tid >> 6;
    const int wm = ((wave >> 1) & 1) * 64, wn = (wave & 1) * 64;
    const int quad = lane >> 4, l15 = lane & 15;
    const unsigned short* ga[4]; const unsigned short* gb[4]; int pw[4];
    #pragma unroll
    for (int c = 0; c < 4; ++c){
        const int mr = (wave*4 + c)*8 + (lane >> 3);
        const int gk = ((lane & 7) - mr) & 7;
        const int s = s0 + mr;
        pw[c] = rowWidth(s) - gk*8;                 // chunk valid iff koff < pw
        ga[c] = P + rowOff(s) + gk*8;
    }
    mk_chunks(VT + bcol, MM, n0, wave, lane, gb);
    f32x4 acc[4][4] = {};
    const int NT = (s0 >> 6) + 2;                   // 2y+2, even
    mfma_db<true>(ga, gb, pw, zpad, NT, acc, wave, lane, As0, Bs0, As1, Bs1);

    #pragma unroll
    for (int i = 0; i < 4; ++i){
        #pragma unroll
        for (int r = 0; r < 4; ++r){
            const int s = s0 + wm + i*16 + quad*4 + r;
            const float linv = 1.0f / L[s];
            #pragma unroll
            for (int j = 0; j < 4; ++j){
                const int n = n0 + wn + j*16 + l15;
                C[(size_t)s*DD + n] = f2bfbits(acc[i][j][r] * linv);
            }
        }
    }
}

extern "C" void kernel_launch(void* const* d_in, const int* in_sizes, int n_in,
                              void* d_out, int out_size, void* d_ws, size_t ws_size,
                              hipStream_t stream)
{
    (void)in_sizes; (void)n_in; (void)out_size;
    const float* x   = (const float*)d_in[0];
    const float* bq  = (const float*)d_in[2];
    const float* bk  = (const float*)d_in[4];
    const float* bv  = (const float*)d_in[6];
    const float* bo  = (const float*)d_in[8];
    const float* b1  = (const float*)d_in[10];
    const float* b2  = (const float*)d_in[12];
    const float* g1  = (const float*)d_in[13];
    const float* be1 = (const float*)d_in[14];
    const float* g2  = (const float*)d_in[15];
    const float* be2 = (const float*)d_in[16];
    float* outf = (float*)d_out;

    if (ws_size < (size_t)REQ_WS){
        sentinel_kernel<<<dim3((unsigned)(MD/256)), dim3(256), 0, stream>>>(outf, 1.0e9f);
        return;
    }

    unsigned short* wsb = (unsigned short*)d_ws;
    unsigned short* Qw  = wsb;                 // -> ctx
    unsigned short* Kw  = wsb + MD;            // -> Hb (bf16 residual h)
    unsigned short* VTw = wsb + 2*MD;
    unsigned short* Pw  = wsb + 3*MD;          // packed P -> mid
    unsigned short* WT  = wsb + WT_OFF;
    unsigned short* ZP  = wsb + ZP_OFF;
    float*          Lf  = (float*)(wsb + LF_OFF);
    unsigned short* Hb  = Kw;                  // h bf16 (Kw last read in scores)
    unsigned short* CTX = Qw;
    unsigned short* MIDw= Pw;
    unsigned short* LN  = (unsigned short*)d_out;   // LN1/LN2 scratch in d_out

    PrepArgs pa;
    static const int widx[6] = {1,3,5,7,9,11};
    for (int i = 0; i < 6; ++i){
        pa.wp.w[i] = (const float*)d_in[widx[i]];
        pa.wp.o[i] = WT + (size_t)i*DD*DD;
    }
    pa.wp.zp = ZP;
    pa.wp.lf = Lf;
    pa.x = x; pa.g1 = g1; pa.be1 = be1; pa.ln = LN;
    unsigned short* WqT = pa.wp.o[0]; unsigned short* WkT = pa.wp.o[1];
    unsigned short* WvT = pa.wp.o[2]; unsigned short* WoT = pa.wp.o[3];
    unsigned short* W1T = pa.wp.o[4]; unsigned short* W2T = pa.wp.o[5];

    const dim3 blk(256);
    const float scale = 1.0f / sqrtf((float)SS);
    const dim3 gA(DD/128, MM/128);    // (8,64)

    // fused wtrans + LN1 (independent streams, one launch)
    prep<<<dim3(1536 + MM), blk, 0, stream>>>(pa);
    // fused Q + K + VT projections (1536 uniform tiles, one launch)
    proj_fused<<<dim3(1536), blk, 0, stream>>>(LN, WqT, WkT, WvT, bq, bk, bv, Qw, Kw, VTw);
    // attention: fused exp-scores (+row sums, triangular-packed) then PV (/rowsum)
    scores_mfma<<<dim3(544), blk, 0, stream>>>(Qw, Kw, Pw, Lf, scale);
    pv_mfma<<<dim3(DD/128, SS/128, BB), blk, 0, stream>>>(Pw, VTw, CTX, ZP, Lf);
    // h = ctx*WoT^T + bo + x -> bf16 Hb (halves h write + both later reads)
    gemm_mfma<false,true,false,false,false><<<gA, blk, 0, stream>>>(CTX, WoT, bo, x, nullptr, Hb, nullptr, DD, DD, DD, DD);
    ln_bf16<<<dim3(MM), blk, 0, stream>>>(Hb, g2, be2, LN);
    // mid = relu(LN*W1T^T + b1)
    gemm_mfma<true,false,false,false,false><<<gA, blk, 0, stream>>>(LN, W1T, b1, nullptr, nullptr, MIDw, nullptr, DD, DD, DD, DD);
    // out = mid*W2T^T + b2 + h (bf16 residual)
    gemm_mfma<false,false,true,true,false><<<gA, blk, 0, stream>>>(MIDw, W2T, b2, nullptr, Hb, nullptr, outf, DD, DD, DD, DD);
}